// Round 5
// baseline (1042.695 us; speedup 1.0000x reference)
//
#include <hip/hip_runtime.h>
#include <hip/hip_bf16.h>
#include <math.h>

// Problem dims
#define S_LEN   4096
#define B_SZ    2
#define E_DIM   1024
#define H_HEADS 8
#define R_ROUNDS 2
#define C_CHUNK 64
#define D_HEAD  128
#define NC_CHUNKS 64
#define QV_STRIDE 2048              // q (1024) | v (1024) per row
#define SCALE_F 0.08838834764831845f
#define NEG_F (-1e9f)
#define NEG_SELF_F (-1e5f)

// LDS column remap for 128-wide fp32 GEMM tiles
__device__ inline int sm_col(int c){ return ((c & 4) << 4) | ((c >> 3) << 2) | (c & 3); }

// ---------- fp32 tiled GEMM: C[M,N] = A[M,K] * W[N,K]^T + bias ----------
// Per-output accumulation is a SINGLE fp32 FMA chain with k strictly
// ascending — deliberately mirrors CPU sgemm microkernels (Eigen/oneDNN/
// OpenBLAS all keep one accumulator per C element, k ascending, FMA), so the
// q values feeding the discrete hash argmax match the reference's rounding.
__global__ __launch_bounds__(256) void gemm_f32_kernel(
    const float* __restrict__ A, const float* __restrict__ W0, const float* __restrict__ b0,
    const float* __restrict__ W1, const float* __restrict__ b1, int nsplit,
    float* __restrict__ Cout, int N, int K)
{
  __shared__ float a_s[32][132];
  __shared__ float w_s[32][132];
  const int t  = threadIdx.x;
  const int n0 = blockIdx.x * 128;
  const int m0 = blockIdx.y * 128;
  const int tx = t & 15, ty = t >> 4;

  float acc[8][8];
  #pragma unroll
  for (int i=0;i<8;i++)
    #pragma unroll
    for (int j=0;j<8;j++) acc[i][j]=0.f;

  const int srow = t >> 3;        // 0..31
  const int scol = (t & 7) * 4;   // 0..28

  for (int kt = 0; kt < K; kt += 32) {
    #pragma unroll
    for (int ii=0; ii<4; ii++) {
      int row = srow + ii*32;
      int pc  = sm_col(row);
      const float4 va = *(const float4*)(A + (size_t)(m0+row)*K + kt + scol);
      a_s[scol+0][pc]=va.x; a_s[scol+1][pc]=va.y; a_s[scol+2][pc]=va.z; a_s[scol+3][pc]=va.w;
      int wrow = n0 + row;
      const float* Wp = (wrow < nsplit) ? (W0 + (size_t)wrow*K) : (W1 + (size_t)(wrow-nsplit)*K);
      const float4 vw = *(const float4*)(Wp + kt + scol);
      w_s[scol+0][pc]=vw.x; w_s[scol+1][pc]=vw.y; w_s[scol+2][pc]=vw.z; w_s[scol+3][pc]=vw.w;
    }
    __syncthreads();
    #pragma unroll 4
    for (int kk=0; kk<32; kk++) {
      float4 a0 = *(const float4*)&a_s[kk][ty*4];
      float4 a1 = *(const float4*)&a_s[kk][64 + ty*4];
      float4 w0v = *(const float4*)&w_s[kk][tx*4];
      float4 w1v = *(const float4*)&w_s[kk][64 + tx*4];
      float am[8] = {a0.x,a0.y,a0.z,a0.w,a1.x,a1.y,a1.z,a1.w};
      float wm[8] = {w0v.x,w0v.y,w0v.z,w0v.w,w1v.x,w1v.y,w1v.z,w1v.w};
      #pragma unroll
      for (int i=0;i<8;i++)
        #pragma unroll
        for (int j=0;j<8;j++)
          acc[i][j] = fmaf(am[i], wm[j], acc[i][j]);
    }
    __syncthreads();
  }
  float bias[8];
  #pragma unroll
  for (int j=0;j<8;j++){
    int n = n0 + tx*8 + j;
    bias[j] = (n < nsplit) ? b0[n] : b1[n-nsplit];
  }
  #pragma unroll
  for (int i=0;i<8;i++){
    int row = m0 + ty*8 + i;
    float4 o0 = {acc[i][0]+bias[0], acc[i][1]+bias[1], acc[i][2]+bias[2], acc[i][3]+bias[3]};
    float4 o1 = {acc[i][4]+bias[4], acc[i][5]+bias[5], acc[i][6]+bias[6], acc[i][7]+bias[7]};
    *(float4*)(Cout + (size_t)row*N + n0 + tx*8)     = o0;
    *(float4*)(Cout + (size_t)row*N + n0 + tx*8 + 4) = o1;
  }
}

// ---------- per-row norm over E: invn (for attention) + nrm (for hash) ----------
__global__ __launch_bounds__(256) void invnorm_kernel(const float* __restrict__ qv,
                                                      float* __restrict__ invn,
                                                      float* __restrict__ nrm)
{
  int row = blockIdx.x;
  int t = threadIdx.x;
  float4 v = *(const float4*)(qv + (size_t)row*QV_STRIDE + t*4);
  float ss = v.x*v.x + v.y*v.y + v.z*v.z + v.w*v.w;
  #pragma unroll
  for (int off=32; off; off>>=1) ss += __shfl_down(ss, off);
  __shared__ float part[4];
  if ((t & 63)==0) part[t>>6] = ss;
  __syncthreads();
  if (t==0){
    float n = sqrtf(part[0]+part[1]+part[2]+part[3]);
    nrm[row]  = n;          // norm order vs ref only perturbs k by a common
    invn[row] = 1.0f/n;     // scale + <=1ulp/element: argmax-invariant.
  }
}

// ---------- fp32 hash path, reference-order mimicry ----------
// lin[m] = sum_{d=0..127} (q_d / n) * hash_w[r,h,d,m], single fp32 FMA chain
// ascending in d; k via true fp32 DIVISION (ref: k = q/||q||). argmax over
// [lin, -lin] in fp32 with first-max tie-break, matching jnp.argmax.
__global__ __launch_bounds__(256) void hash32_kernel(
    const float* __restrict__ qv, const float* __restrict__ nrm,
    const float* __restrict__ hw, int* __restrict__ hashes)
{
  int idx = blockIdx.x*256 + threadIdx.x;   // [B,R,H,S] = 131072
  int s = idx & (S_LEN-1);
  int h = (idx >> 12) & 7;
  int r = (idx >> 15) & 1;
  int b = idx >> 16;
  const float* qr = qv + (size_t)(s*B_SZ + b)*QV_STRIDE + h*D_HEAD;
  const float  n  = nrm[s*B_SZ + b];
  const float* wp = hw + (size_t)(r*H_HEADS + h)*D_HEAD*8;
  float lin[8];
  #pragma unroll
  for (int m=0;m<8;m++) lin[m]=0.f;
  for (int d=0; d<D_HEAD; d++){
    float kd = qr[d] / n;                   // fp32 division, per reference
    #pragma unroll
    for (int m=0;m<8;m++) lin[m] = fmaf(kd, wp[d*8+m], lin[m]);
  }
  float best = lin[0]; int bi = 0;
  #pragma unroll
  for (int m=1;m<8;m++) if (lin[m] > best){ best=lin[m]; bi=m; }
  #pragma unroll
  for (int m=0;m<8;m++) if (-lin[m] > best){ best=-lin[m]; bi=8+m; }
  hashes[idx] = bi;
}

// ---------- stable counting sort by bucket, per (b,r,h) ----------
__global__ __launch_bounds__(256) void sort_kernel(const int* __restrict__ hashes,
                                                   int* __restrict__ sidx,
                                                   unsigned short* __restrict__ hs_pack)
{
  __shared__ unsigned char bucket_s[S_LEN];
  __shared__ int counts[16][257];
  __shared__ int bbase[16];
  int t = threadIdx.x;
  size_t base = (size_t)blockIdx.x * S_LEN;
  for (int e=0;e<16;e++) bucket_s[t + e*256] = (unsigned char)hashes[base + t + e*256];
  #pragma unroll
  for (int u=0;u<16;u++) counts[u][t]=0;
  if (t<16) counts[t][256]=0;
  __syncthreads();
  int s0 = t*16;
  for (int e=0;e<16;e++){ int u = bucket_s[s0+e]; counts[u][t]++; }
  __syncthreads();
  if (t < 16){
    int run=0;
    for (int tt=0; tt<256; tt++){ int c = counts[t][tt]; counts[t][tt]=run; run+=c; }
    counts[t][256]=run;
  }
  __syncthreads();
  if (t==0){
    int run=0;
    for (int u=0;u<16;u++){ bbase[u]=run; run += counts[u][256]; }
  }
  __syncthreads();
  for (int e=0;e<16;e++){
    int s = s0+e; int u = bucket_s[s];
    int pos = bbase[u] + counts[u][t]; counts[u][t]++;
    sidx[base+pos] = s;
    hs_pack[base+pos] = (unsigned short)(s | (u<<12));
  }
}

// ---------- chunked LSH attention, FP32 end-to-end, online softmax ----------
// Reference quirk (silent broadcast): for query at sorted position p=n*64+c,
// scores/values use win(n), but BOTH masks compare vs win(c):
// keep iff bucket[p]==bucket[win(c),w]; NEG_SELF iff id[p]==id[win(c),w].
// K-dim split in two 64-wide halves so fp32 Q/KV/P fit in 64 KB LDS.
#define QK_ST 68
__device__ inline int swz(int row, int g){ return row*QK_ST + ((g ^ (row>>3))<<2); }

__global__ __launch_bounds__(256) void attn_kernel(
    const float* __restrict__ qv, const float* __restrict__ invn,
    const int* __restrict__ sidx, const unsigned short* __restrict__ hs_pack,
    float* __restrict__ o_r, float* __restrict__ lse_g)
{
  __shared__ float q_s[64*QK_ST];       // fp32 scaled queries, one 64-d half
  __shared__ float kv_s[64*QK_ST];      // fp32 keys/values, one 64-d half
  __shared__ float p_s[64*66];
  __shared__ __align__(16) unsigned short pack_s[S_LEN];  // id | bucket<<12
  __shared__ int iw_s[192];
  __shared__ float alpha_s[64];
  __shared__ float l_s[64];

  const int t = threadIdx.x;
  const int bid = blockIdx.x;
  const int nc = bid & 63;
  const int h  = (bid >> 6) & 7;
  const int r  = (bid >> 9) & 1;
  const int b  = bid >> 10;
  const size_t base_s = (size_t)((b*R_ROUNDS + r)*H_HEADS + h) * S_LEN;

  {
    const uint4* src = (const uint4*)(hs_pack + base_s);   // 512 uint4
    uint4* dst = (uint4*)pack_s;
    dst[t]       = src[t];
    dst[256 + t] = src[256 + t];
  }
  if (t < 192) {
    int w = t >> 6, j = t & 63;
    int cw = (nc + w + NC_CHUNKS - 1) % NC_CHUNKS;   // chunks n-1, n, n+1
    iw_s[t] = sidx[base_s + cw*C_CHUNK + j];
  }
  __syncthreads();

  const int ip = t >> 3, jo = t & 7;
  const int r0 = ip*2, r1 = ip*2+1;
  const int pvi = t >> 2, pvd = t & 3;
  const unsigned pq0 = pack_s[nc*64 + r0], pq1 = pack_s[nc*64 + r1];
  const unsigned hq0 = pq0 >> 12,   hq1 = pq1 >> 12;
  const unsigned iq0 = pq0 & 0xfffu, iq1 = pq1 & 0xfffu;

  float m_run0 = -3e38f, m_run1 = -3e38f, l_run0 = 0.f, l_run1 = 0.f;
  float oacc[4][8];
  #pragma unroll
  for (int k=0;k<4;k++)
    #pragma unroll
    for (int e=0;e<8;e++) oacc[k][e]=0.f;

  for (int w=0; w<3; w++){
    float sv0[8], sv1[8];
    #pragma unroll
    for (int jj=0;jj<8;jj++){ sv0[jj]=0.f; sv1[jj]=0.f; }

    // ---- scores: two 64-d halves ----
    for (int dh=0; dh<2; dh++){
      __syncthreads();   // prev users of q_s/kv_s done
      #pragma unroll
      for (int ii=0; ii<4; ii++){
        int l = ii*256 + t;              // 0..1023 float4 slots
        int row = l >> 4, g = l & 15;
        int qi = iw_s[64 + row];
        const float4 fq = *(const float4*)(qv + (size_t)(qi*B_SZ + b)*QV_STRIDE + h*D_HEAD + dh*64 + g*4);
        float4 oq = {fq.x*SCALE_F, fq.y*SCALE_F, fq.z*SCALE_F, fq.w*SCALE_F};
        *(float4*)&q_s[swz(row,g)] = oq;
        int kj = iw_s[w*64 + row];
        float sc = invn[kj*B_SZ + b];
        const float4 fk = *(const float4*)(qv + (size_t)(kj*B_SZ + b)*QV_STRIDE + h*D_HEAD + dh*64 + g*4);
        float4 ok = {fk.x*sc, fk.y*sc, fk.z*sc, fk.w*sc};
        *(float4*)&kv_s[swz(row,g)] = ok;
      }
      __syncthreads();
      #pragma unroll 4
      for (int g=0; g<16; g++){
        float4 a0 = *(const float4*)&q_s[swz(r0,g)];
        float4 a1 = *(const float4*)&q_s[swz(r1,g)];
        #pragma unroll
        for (int jj=0;jj<8;jj++){
          int j = jo*8+jj;
          float4 kf = *(const float4*)&kv_s[swz(j,g)];
          sv0[jj] = fmaf(a0.x,kf.x, fmaf(a0.y,kf.y, fmaf(a0.z,kf.z, fmaf(a0.w,kf.w, sv0[jj]))));
          sv1[jj] = fmaf(a1.x,kf.x, fmaf(a1.y,kf.y, fmaf(a1.z,kf.z, fmaf(a1.w,kf.w, sv1[jj]))));
        }
      }
    }

    // ---- masks (transposed reference semantics: source = win(c)) ----
    {
      const int mc0 = (r0 + w + 63) & 63;
      const int mc1 = (r1 + w + 63) & 63;
      uint4 u0 = *(const uint4*)&pack_s[mc0*64 + jo*8];
      uint4 u1 = *(const uint4*)&pack_s[mc1*64 + jo*8];
      const unsigned short* pk0 = (const unsigned short*)&u0;
      const unsigned short* pk1 = (const unsigned short*)&u1;
      #pragma unroll
      for (int jj=0;jj<8;jj++){
        unsigned e0 = pk0[jj], e1 = pk1[jj];
        float a0 = ((e0>>12)==hq0)? sv0[jj] : NEG_F;  if ((e0&0xfffu)==iq0) a0 = NEG_SELF_F;
        float a1 = ((e1>>12)==hq1)? sv1[jj] : NEG_F;  if ((e1&0xfffu)==iq1) a1 = NEG_SELF_F;
        sv0[jj]=a0; sv1[jj]=a1;
      }
    }

    // ---- online softmax (row state replicated across 8 jo-lanes) ----
    float mx0 = sv0[0], mx1 = sv1[0];
    #pragma unroll
    for (int jj=1;jj<8;jj++){ mx0=fmaxf(mx0,sv0[jj]); mx1=fmaxf(mx1,sv1[jj]); }
    #pragma unroll
    for (int off=1; off<8; off<<=1){ mx0=fmaxf(mx0,__shfl_xor(mx0,off)); mx1=fmaxf(mx1,__shfl_xor(mx1,off)); }
    float mn0 = fmaxf(m_run0, mx0), mn1 = fmaxf(m_run1, mx1);
    float al0 = expf(m_run0 - mn0), al1 = expf(m_run1 - mn1);
    float ss0 = 0.f, ss1 = 0.f;
    #pragma unroll
    for (int jj=0;jj<8;jj++){
      float p0 = expf(sv0[jj]-mn0), p1 = expf(sv1[jj]-mn1);
      ss0 += p0; ss1 += p1;
      p_s[r0*66 + jo*8+jj] = p0;
      p_s[r1*66 + jo*8+jj] = p1;
    }
    #pragma unroll
    for (int off=1; off<8; off<<=1){ ss0 += __shfl_xor(ss0,off); ss1 += __shfl_xor(ss1,off); }
    l_run0 = l_run0*al0 + ss0;  l_run1 = l_run1*al1 + ss1;
    m_run0 = mn0; m_run1 = mn1;
    if (jo==0){ alpha_s[r0] = al0; alpha_s[r1] = al1; }

    // ---- PV: two 64-d value halves ----
    for (int dh=0; dh<2; dh++){
      __syncthreads();   // p_s/alpha visible (dh=0); kv_s free
      #pragma unroll
      for (int ii=0; ii<4; ii++){
        int l = ii*256 + t;
        int row = l >> 4, g = l & 15;
        int kj = iw_s[w*64 + row];
        const float4 fv = *(const float4*)(qv + (size_t)(kj*B_SZ + b)*QV_STRIDE + 1024 + h*D_HEAD + dh*64 + g*4);
        *(float4*)&kv_s[swz(row,g)] = fv;
      }
      __syncthreads();

      if (dh==0){
        float av = alpha_s[pvi];
        #pragma unroll
        for (int k=0;k<4;k++)
          #pragma unroll
          for (int e=0;e<8;e++) oacc[k][e] *= av;
      }
      const float* prow = &p_s[pvi*66];
      #pragma unroll 4
      for (int jj=0;jj<64;jj++){
        float p = prow[jj];
        #pragma unroll
        for (int kk=0;kk<2;kk++){
          int k = 2*dh + kk;
          int g0 = 2*pvd + 8*kk;       // d-local group within this half
          float4 v0 = *(const float4*)&kv_s[swz(jj,g0)];
          float4 v1 = *(const float4*)&kv_s[swz(jj,g0+1)];
          oacc[k][0] = fmaf(p, v0.x, oacc[k][0]);
          oacc[k][1] = fmaf(p, v0.y, oacc[k][1]);
          oacc[k][2] = fmaf(p, v0.z, oacc[k][2]);
          oacc[k][3] = fmaf(p, v0.w, oacc[k][3]);
          oacc[k][4] = fmaf(p, v1.x, oacc[k][4]);
          oacc[k][5] = fmaf(p, v1.y, oacc[k][5]);
          oacc[k][6] = fmaf(p, v1.z, oacc[k][6]);
          oacc[k][7] = fmaf(p, v1.w, oacc[k][7]);
        }
      }
    }
  }

  if (jo==0){
    l_s[r0] = l_run0; l_s[r1] = l_run1;
    lse_g[base_s + iq0] = m_run0 + logf(l_run0);
    lse_g[base_s + iq1] = m_run1 + logf(l_run1);
  }
  __syncthreads();
  float invl = 1.0f / l_s[pvi];
  int oi = iw_s[64 + pvi];
  float* orow = o_r + (base_s + oi)*(size_t)D_HEAD;
  #pragma unroll
  for (int k=0;k<4;k++){
    float4 v0 = {oacc[k][0]*invl, oacc[k][1]*invl, oacc[k][2]*invl, oacc[k][3]*invl};
    float4 v1 = {oacc[k][4]*invl, oacc[k][5]*invl, oacc[k][6]*invl, oacc[k][7]*invl};
    *(float4*)(orow + pvd*8 + k*32)     = v0;
    *(float4*)(orow + pvd*8 + k*32 + 4) = v1;
  }
}

// ---------- combine rounds: softmax over per-round LSE ----------
__global__ __launch_bounds__(256) void combine_kernel(const float* __restrict__ o_r,
                                                      const float* __restrict__ lse,
                                                      float* __restrict__ ocomb)
{
  int gid = blockIdx.x*256 + threadIdx.x;   // B*H*S*32
  int q4 = gid & 31;
  int tokenid = gid >> 5;
  int s = tokenid & (S_LEN-1);
  int h = (tokenid >> 12) & 7;
  int b = tokenid >> 15;
  size_t i0 = (size_t)((b*2 + 0)*8 + h)*S_LEN + s;
  size_t i1 = (size_t)((b*2 + 1)*8 + h)*S_LEN + s;
  float l0 = lse[i0], l1 = lse[i1];
  float m = fmaxf(l0,l1);
  float w0 = expf(l0-m), w1 = expf(l1-m);
  float inv = 1.0f/(w0+w1);
  w0*=inv; w1*=inv;
  float4 a = *(const float4*)(o_r + i0*D_HEAD + q4*4);
  float4 c = *(const float4*)(o_r + i1*D_HEAD + q4*4);
  float4 o = {w0*a.x + w1*c.x, w0*a.y + w1*c.y, w0*a.z + w1*c.z, w0*a.w + w1*c.w};
  *(float4*)(ocomb + (size_t)(s*B_SZ + b)*E_DIM + h*D_HEAD + q4*4) = o;
}

// ---------- launch ----------
extern "C" void kernel_launch(void* const* d_in, const int* in_sizes, int n_in,
                              void* d_out, int out_size, void* d_ws, size_t ws_size,
                              hipStream_t stream)
{
  (void)in_sizes; (void)n_in; (void)out_size; (void)ws_size;
  const float* x  = (const float*)d_in[0];
  const float* wq = (const float*)d_in[1];
  const float* bq = (const float*)d_in[2];
  const float* wv = (const float*)d_in[3];
  const float* bv = (const float*)d_in[4];
  const float* wo = (const float*)d_in[5];
  const float* bo = (const float*)d_in[6];
  const float* hw = (const float*)d_in[7];
  float* out = (float*)d_out;

  float* ws    = (float*)d_ws;
  float* qv    = ws;                          // [8192][2048] q|v
  float* invn  = ws + 16777216;               // [8192]
  float* nrm   = ws + 16785408;               // [8192]
  int*   hashes= (int*)(ws + 16793600);       // [B,R,H,S]
  int*   sidx  = (int*)(ws + 16924672);       // [B,R,H,S]
  float* lse   = ws + 17055744;               // [B,R,H,S]
  float* o_r   = ws + 17186816;               // [B,R,H,S,128]
  float* ocomb = ws + 33964032;               // [8192][1024]
  unsigned short* hs_pack = (unsigned short*)(ws + 42352640);  // [B,R,H,S] packed

  gemm_f32_kernel<<<dim3(16,64), 256, 0, stream>>>(x, wq, bq, wv, bv, 1024, qv, 2048, 1024);
  invnorm_kernel<<<dim3(8192), 256, 0, stream>>>(qv, invn, nrm);
  hash32_kernel<<<dim3(512), 256, 0, stream>>>(qv, nrm, hw, hashes);
  sort_kernel<<<dim3(32), 256, 0, stream>>>(hashes, sidx, hs_pack);
  attn_kernel<<<dim3(2048), 256, 0, stream>>>(qv, invn, sidx, hs_pack, o_r, lse);
  combine_kernel<<<dim3(8192), 256, 0, stream>>>(o_r, lse, ocomb);
  gemm_f32_kernel<<<dim3(8,64), 256, 0, stream>>>(ocomb, wo, bo, wo, bo, 1<<30, out, 1024, 1024);
}

// Round 6
// 850.725 us; speedup vs baseline: 1.2257x; 1.2257x over previous
//
#include <hip/hip_runtime.h>
#include <hip/hip_bf16.h>
#include <math.h>

// Problem dims
#define S_LEN   4096
#define B_SZ    2
#define E_DIM   1024
#define H_HEADS 8
#define R_ROUNDS 2
#define C_CHUNK 64
#define D_HEAD  128
#define NC_CHUNKS 64
#define QV_STRIDE 2048              // q (1024) | v (1024) per row
#define SCALE_F 0.08838834764831845f
#define NEG_F (-1e9f)
#define NEG_SELF_F (-1e5f)

typedef __attribute__((ext_vector_type(8))) short short8;
typedef __attribute__((ext_vector_type(4))) float f32x4;

// fp32 -> bf16 (RNE) bit pattern
__device__ inline unsigned bfr(float x){
  unsigned u = __float_as_uint(x);
  return (u + 0x7fffu + ((u >> 16) & 1u)) >> 16;
}
__device__ inline unsigned bpack2(float a, float b){ return bfr(a) | (bfr(b) << 16); }

// LDS column remap for 128-wide fp32 GEMM tiles
__device__ inline int sm_col(int c){ return ((c & 4) << 4) | ((c >> 3) << 2) | (c & 3); }

// ---------- fp32 tiled GEMM: C[M,N] = A[M,K] * W[N,K]^T + bias ----------
// ONLY used for the q projection. Per-output accumulation is a SINGLE fp32
// FMA chain with k strictly ascending — mirrors CPU sgemm microkernels so the
// q values feeding the discrete hash argmax match the reference's rounding.
// DO NOT change the arithmetic (R5 pass depends on it); ldc touches stores only.
__global__ __launch_bounds__(256) void gemm_f32_kernel(
    const float* __restrict__ A, const float* __restrict__ W0, const float* __restrict__ b0,
    const float* __restrict__ W1, const float* __restrict__ b1, int nsplit,
    float* __restrict__ Cout, int N, int K, int ldc)
{
  __shared__ float a_s[32][132];
  __shared__ float w_s[32][132];
  const int t  = threadIdx.x;
  const int n0 = blockIdx.x * 128;
  const int m0 = blockIdx.y * 128;
  const int tx = t & 15, ty = t >> 4;

  float acc[8][8];
  #pragma unroll
  for (int i=0;i<8;i++)
    #pragma unroll
    for (int j=0;j<8;j++) acc[i][j]=0.f;

  const int srow = t >> 3;        // 0..31
  const int scol = (t & 7) * 4;   // 0..28

  for (int kt = 0; kt < K; kt += 32) {
    #pragma unroll
    for (int ii=0; ii<4; ii++) {
      int row = srow + ii*32;
      int pc  = sm_col(row);
      const float4 va = *(const float4*)(A + (size_t)(m0+row)*K + kt + scol);
      a_s[scol+0][pc]=va.x; a_s[scol+1][pc]=va.y; a_s[scol+2][pc]=va.z; a_s[scol+3][pc]=va.w;
      int wrow = n0 + row;
      const float* Wp = (wrow < nsplit) ? (W0 + (size_t)wrow*K) : (W1 + (size_t)(wrow-nsplit)*K);
      const float4 vw = *(const float4*)(Wp + kt + scol);
      w_s[scol+0][pc]=vw.x; w_s[scol+1][pc]=vw.y; w_s[scol+2][pc]=vw.z; w_s[scol+3][pc]=vw.w;
    }
    __syncthreads();
    #pragma unroll 4
    for (int kk=0; kk<32; kk++) {
      float4 a0 = *(const float4*)&a_s[kk][ty*4];
      float4 a1 = *(const float4*)&a_s[kk][64 + ty*4];
      float4 w0v = *(const float4*)&w_s[kk][tx*4];
      float4 w1v = *(const float4*)&w_s[kk][64 + tx*4];
      float am[8] = {a0.x,a0.y,a0.z,a0.w,a1.x,a1.y,a1.z,a1.w};
      float wm[8] = {w0v.x,w0v.y,w0v.z,w0v.w,w1v.x,w1v.y,w1v.z,w1v.w};
      #pragma unroll
      for (int i=0;i<8;i++)
        #pragma unroll
        for (int j=0;j<8;j++)
          acc[i][j] = fmaf(am[i], wm[j], acc[i][j]);
    }
    __syncthreads();
  }
  float bias[8];
  #pragma unroll
  for (int j=0;j<8;j++){
    int n = n0 + tx*8 + j;
    bias[j] = (n < nsplit) ? b0[n] : b1[n-nsplit];
  }
  #pragma unroll
  for (int i=0;i<8;i++){
    int row = m0 + ty*8 + i;
    float4 o0 = {acc[i][0]+bias[0], acc[i][1]+bias[1], acc[i][2]+bias[2], acc[i][3]+bias[3]};
    float4 o1 = {acc[i][4]+bias[4], acc[i][5]+bias[5], acc[i][6]+bias[6], acc[i][7]+bias[7]};
    *(float4*)(Cout + (size_t)row*ldc + n0 + tx*8)     = o0;
    *(float4*)(Cout + (size_t)row*ldc + n0 + tx*8 + 4) = o1;
  }
}

// ---------- bf16 MFMA GEMM: C[M,N] = A[M,K]*W[N,K]^T + bias (smooth paths) ----------
// 128x128 tile/block, 4 waves in 2x2 of 64x64, mfma_f32_16x16x32_bf16.
// A/W are fp32 in HBM; converted to bf16 (RNE) during LDS staging.
// Fragment layouts (HW-verified per guide): A/B: elem k = (lane>>4)*8+j of
// row/col (lane&15); C/D: col=lane&15, row=(lane>>4)*4+reg.
#define BST 72   // LDS row stride in ushort (144 B: 16B-aligned, breaks pow2)
__global__ __launch_bounds__(256) void gemm_bf16_kernel(
    const float* __restrict__ A, const float* __restrict__ W,
    const float* __restrict__ bias, float* __restrict__ C,
    int K, int ldc)
{
  __shared__ unsigned short a_sh[128*BST];
  __shared__ unsigned short w_sh[128*BST];
  const int t = threadIdx.x;
  const int m0 = blockIdx.y * 128, n0 = blockIdx.x * 128;
  const int lane = t & 63, wid = t >> 6;
  const int mw = (wid >> 1) * 64, nw = (wid & 1) * 64;
  const int lr = lane & 15, lg = lane >> 4;

  f32x4 acc[4][4];
  #pragma unroll
  for (int i=0;i<4;i++)
    #pragma unroll
    for (int j=0;j<4;j++) acc[i][j] = (f32x4){0.f,0.f,0.f,0.f};

  const int srow = t >> 3;        // 0..31
  const int scol = (t & 7) * 8;   // 0..56

  for (int kt = 0; kt < K; kt += 64){
    __syncthreads();   // previous iteration's fragment reads done
    #pragma unroll
    for (int ii = 0; ii < 4; ii++){
      int row = srow + ii*32;
      const float4 f0 = *(const float4*)(A + (size_t)(m0+row)*K + kt + scol);
      const float4 f1 = *(const float4*)(A + (size_t)(m0+row)*K + kt + scol + 4);
      uint4 ua = { bpack2(f0.x,f0.y), bpack2(f0.z,f0.w), bpack2(f1.x,f1.y), bpack2(f1.z,f1.w) };
      *(uint4*)&a_sh[row*BST + scol] = ua;
      const float4 g0 = *(const float4*)(W + (size_t)(n0+row)*K + kt + scol);
      const float4 g1 = *(const float4*)(W + (size_t)(n0+row)*K + kt + scol + 4);
      uint4 uw = { bpack2(g0.x,g0.y), bpack2(g0.z,g0.w), bpack2(g1.x,g1.y), bpack2(g1.z,g1.w) };
      *(uint4*)&w_sh[row*BST + scol] = uw;
    }
    __syncthreads();
    #pragma unroll
    for (int ks = 0; ks < 64; ks += 32){
      short8 af[4], bfr_[4];
      #pragma unroll
      for (int i=0;i<4;i++) af[i]   = *(const short8*)&a_sh[(mw + i*16 + lr)*BST + ks + lg*8];
      #pragma unroll
      for (int j=0;j<4;j++) bfr_[j] = *(const short8*)&w_sh[(nw + j*16 + lr)*BST + ks + lg*8];
      #pragma unroll
      for (int i=0;i<4;i++)
        #pragma unroll
        for (int j=0;j<4;j++)
          acc[i][j] = __builtin_amdgcn_mfma_f32_16x16x32_bf16(af[i], bfr_[j], acc[i][j], 0, 0, 0);
    }
  }
  // epilogue: C/D layout col=lane&15, row=(lane>>4)*4+reg
  #pragma unroll
  for (int j=0;j<4;j++){
    int col = n0 + nw + j*16 + lr;
    float bs = bias[col];
    #pragma unroll
    for (int i=0;i<4;i++){
      int rbase = m0 + mw + i*16 + lg*4;
      #pragma unroll
      for (int r=0;r<4;r++)
        C[(size_t)(rbase+r)*ldc + col] = acc[i][j][r] + bs;
    }
  }
}

// ---------- per-row norm over E: invn (for attention) + nrm (for hash) ----------
__global__ __launch_bounds__(256) void invnorm_kernel(const float* __restrict__ qv,
                                                      float* __restrict__ invn,
                                                      float* __restrict__ nrm)
{
  int row = blockIdx.x;
  int t = threadIdx.x;
  float4 v = *(const float4*)(qv + (size_t)row*QV_STRIDE + t*4);
  float ss = v.x*v.x + v.y*v.y + v.z*v.z + v.w*v.w;
  #pragma unroll
  for (int off=32; off; off>>=1) ss += __shfl_down(ss, off);
  __shared__ float part[4];
  if ((t & 63)==0) part[t>>6] = ss;
  __syncthreads();
  if (t==0){
    float n = sqrtf(part[0]+part[1]+part[2]+part[3]);
    nrm[row]  = n;
    invn[row] = 1.0f/n;
  }
}

// ---------- fp32 hash path, reference-order mimicry (DO NOT TOUCH: R5 pass) ----------
__global__ __launch_bounds__(256) void hash32_kernel(
    const float* __restrict__ qv, const float* __restrict__ nrm,
    const float* __restrict__ hw, int* __restrict__ hashes)
{
  int idx = blockIdx.x*256 + threadIdx.x;   // [B,R,H,S] = 131072
  int s = idx & (S_LEN-1);
  int h = (idx >> 12) & 7;
  int r = (idx >> 15) & 1;
  int b = idx >> 16;
  const float* qr = qv + (size_t)(s*B_SZ + b)*QV_STRIDE + h*D_HEAD;
  const float  n  = nrm[s*B_SZ + b];
  const float* wp = hw + (size_t)(r*H_HEADS + h)*D_HEAD*8;
  float lin[8];
  #pragma unroll
  for (int m=0;m<8;m++) lin[m]=0.f;
  for (int d=0; d<D_HEAD; d++){
    float kd = qr[d] / n;                   // fp32 division, per reference
    #pragma unroll
    for (int m=0;m<8;m++) lin[m] = fmaf(kd, wp[d*8+m], lin[m]);
  }
  float best = lin[0]; int bi = 0;
  #pragma unroll
  for (int m=1;m<8;m++) if (lin[m] > best){ best=lin[m]; bi=m; }
  #pragma unroll
  for (int m=0;m<8;m++) if (-lin[m] > best){ best=-lin[m]; bi=8+m; }
  hashes[idx] = bi;
}

// ---------- stable counting sort by bucket, per (b,r,h) ----------
__global__ __launch_bounds__(256) void sort_kernel(const int* __restrict__ hashes,
                                                   int* __restrict__ sidx,
                                                   unsigned short* __restrict__ hs_pack)
{
  __shared__ unsigned char bucket_s[S_LEN];
  __shared__ int counts[16][257];
  __shared__ int bbase[16];
  int t = threadIdx.x;
  size_t base = (size_t)blockIdx.x * S_LEN;
  for (int e=0;e<16;e++) bucket_s[t + e*256] = (unsigned char)hashes[base + t + e*256];
  #pragma unroll
  for (int u=0;u<16;u++) counts[u][t]=0;
  if (t<16) counts[t][256]=0;
  __syncthreads();
  int s0 = t*16;
  for (int e=0;e<16;e++){ int u = bucket_s[s0+e]; counts[u][t]++; }
  __syncthreads();
  if (t < 16){
    int run=0;
    for (int tt=0; tt<256; tt++){ int c = counts[t][tt]; counts[t][tt]=run; run+=c; }
    counts[t][256]=run;
  }
  __syncthreads();
  if (t==0){
    int run=0;
    for (int u=0;u<16;u++){ bbase[u]=run; run += counts[u][256]; }
  }
  __syncthreads();
  for (int e=0;e<16;e++){
    int s = s0+e; int u = bucket_s[s];
    int pos = bbase[u] + counts[u][t]; counts[u][t]++;
    sidx[base+pos] = s;
    hs_pack[base+pos] = (unsigned short)(s | (u<<12));
  }
}

// ---------- chunked LSH attention, FP32 end-to-end, online softmax ----------
// Reference quirk (silent broadcast): for query at sorted position p=n*64+c,
// scores/values use win(n), but BOTH masks compare vs win(c).
#define QK_ST 68
__device__ inline int swz(int row, int g){ return row*QK_ST + ((g ^ (row>>3))<<2); }

__global__ __launch_bounds__(256) void attn_kernel(
    const float* __restrict__ qv, const float* __restrict__ invn,
    const int* __restrict__ sidx, const unsigned short* __restrict__ hs_pack,
    float* __restrict__ o_r, float* __restrict__ lse_g)
{
  __shared__ float q_s[64*QK_ST];       // fp32 scaled queries, one 64-d half
  __shared__ float kv_s[64*QK_ST];      // fp32 keys/values, one 64-d half
  __shared__ float p_s[64*66];
  __shared__ __align__(16) unsigned short pack_s[S_LEN];  // id | bucket<<12
  __shared__ int iw_s[192];
  __shared__ float alpha_s[64];
  __shared__ float l_s[64];

  const int t = threadIdx.x;
  const int bid = blockIdx.x;
  const int nc = bid & 63;
  const int h  = (bid >> 6) & 7;
  const int r  = (bid >> 9) & 1;
  const int b  = bid >> 10;
  const size_t base_s = (size_t)((b*R_ROUNDS + r)*H_HEADS + h) * S_LEN;

  {
    const uint4* src = (const uint4*)(hs_pack + base_s);   // 512 uint4
    uint4* dst = (uint4*)pack_s;
    dst[t]       = src[t];
    dst[256 + t] = src[256 + t];
  }
  if (t < 192) {
    int w = t >> 6, j = t & 63;
    int cw = (nc + w + NC_CHUNKS - 1) % NC_CHUNKS;   // chunks n-1, n, n+1
    iw_s[t] = sidx[base_s + cw*C_CHUNK + j];
  }
  __syncthreads();

  const int ip = t >> 3, jo = t & 7;
  const int r0 = ip*2, r1 = ip*2+1;
  const int pvi = t >> 2, pvd = t & 3;
  const unsigned pq0 = pack_s[nc*64 + r0], pq1 = pack_s[nc*64 + r1];
  const unsigned hq0 = pq0 >> 12,   hq1 = pq1 >> 12;
  const unsigned iq0 = pq0 & 0xfffu, iq1 = pq1 & 0xfffu;

  float m_run0 = -3e38f, m_run1 = -3e38f, l_run0 = 0.f, l_run1 = 0.f;
  float oacc[4][8];
  #pragma unroll
  for (int k=0;k<4;k++)
    #pragma unroll
    for (int e=0;e<8;e++) oacc[k][e]=0.f;

  for (int w=0; w<3; w++){
    float sv0[8], sv1[8];
    #pragma unroll
    for (int jj=0;jj<8;jj++){ sv0[jj]=0.f; sv1[jj]=0.f; }

    // ---- scores: two 64-d halves ----
    for (int dh=0; dh<2; dh++){
      __syncthreads();
      #pragma unroll
      for (int ii=0; ii<4; ii++){
        int l = ii*256 + t;
        int row = l >> 4, g = l & 15;
        int qi = iw_s[64 + row];
        const float4 fq = *(const float4*)(qv + (size_t)(qi*B_SZ + b)*QV_STRIDE + h*D_HEAD + dh*64 + g*4);
        float4 oq = {fq.x*SCALE_F, fq.y*SCALE_F, fq.z*SCALE_F, fq.w*SCALE_F};
        *(float4*)&q_s[swz(row,g)] = oq;
        int kj = iw_s[w*64 + row];
        float sc = invn[kj*B_SZ + b];
        const float4 fk = *(const float4*)(qv + (size_t)(kj*B_SZ + b)*QV_STRIDE + h*D_HEAD + dh*64 + g*4);
        float4 ok = {fk.x*sc, fk.y*sc, fk.z*sc, fk.w*sc};
        *(float4*)&kv_s[swz(row,g)] = ok;
      }
      __syncthreads();
      #pragma unroll 4
      for (int g=0; g<16; g++){
        float4 a0 = *(const float4*)&q_s[swz(r0,g)];
        float4 a1 = *(const float4*)&q_s[swz(r1,g)];
        #pragma unroll
        for (int jj=0;jj<8;jj++){
          int j = jo*8+jj;
          float4 kf = *(const float4*)&kv_s[swz(j,g)];
          sv0[jj] = fmaf(a0.x,kf.x, fmaf(a0.y,kf.y, fmaf(a0.z,kf.z, fmaf(a0.w,kf.w, sv0[jj]))));
          sv1[jj] = fmaf(a1.x,kf.x, fmaf(a1.y,kf.y, fmaf(a1.z,kf.z, fmaf(a1.w,kf.w, sv1[jj]))));
        }
      }
    }

    // ---- masks (transposed reference semantics: source = win(c)) ----
    {
      const int mc0 = (r0 + w + 63) & 63;
      const int mc1 = (r1 + w + 63) & 63;
      uint4 u0 = *(const uint4*)&pack_s[mc0*64 + jo*8];
      uint4 u1 = *(const uint4*)&pack_s[mc1*64 + jo*8];
      const unsigned short* pk0 = (const unsigned short*)&u0;
      const unsigned short* pk1 = (const unsigned short*)&u1;
      #pragma unroll
      for (int jj=0;jj<8;jj++){
        unsigned e0 = pk0[jj], e1 = pk1[jj];
        float a0 = ((e0>>12)==hq0)? sv0[jj] : NEG_F;  if ((e0&0xfffu)==iq0) a0 = NEG_SELF_F;
        float a1 = ((e1>>12)==hq1)? sv1[jj] : NEG_F;  if ((e1&0xfffu)==iq1) a1 = NEG_SELF_F;
        sv0[jj]=a0; sv1[jj]=a1;
      }
    }

    // ---- online softmax (row state replicated across 8 jo-lanes) ----
    float mx0 = sv0[0], mx1 = sv1[0];
    #pragma unroll
    for (int jj=1;jj<8;jj++){ mx0=fmaxf(mx0,sv0[jj]); mx1=fmaxf(mx1,sv1[jj]); }
    #pragma unroll
    for (int off=1; off<8; off<<=1){ mx0=fmaxf(mx0,__shfl_xor(mx0,off)); mx1=fmaxf(mx1,__shfl_xor(mx1,off)); }
    float mn0 = fmaxf(m_run0, mx0), mn1 = fmaxf(m_run1, mx1);
    float al0 = expf(m_run0 - mn0), al1 = expf(m_run1 - mn1);
    float ss0 = 0.f, ss1 = 0.f;
    #pragma unroll
    for (int jj=0;jj<8;jj++){
      float p0 = expf(sv0[jj]-mn0), p1 = expf(sv1[jj]-mn1);
      ss0 += p0; ss1 += p1;
      p_s[r0*66 + jo*8+jj] = p0;
      p_s[r1*66 + jo*8+jj] = p1;
    }
    #pragma unroll
    for (int off=1; off<8; off<<=1){ ss0 += __shfl_xor(ss0,off); ss1 += __shfl_xor(ss1,off); }
    l_run0 = l_run0*al0 + ss0;  l_run1 = l_run1*al1 + ss1;
    m_run0 = mn0; m_run1 = mn1;
    if (jo==0){ alpha_s[r0] = al0; alpha_s[r1] = al1; }

    // ---- PV: two 64-d value halves ----
    for (int dh=0; dh<2; dh++){
      __syncthreads();
      #pragma unroll
      for (int ii=0; ii<4; ii++){
        int l = ii*256 + t;
        int row = l >> 4, g = l & 15;
        int kj = iw_s[w*64 + row];
        const float4 fv = *(const float4*)(qv + (size_t)(kj*B_SZ + b)*QV_STRIDE + 1024 + h*D_HEAD + dh*64 + g*4);
        *(float4*)&kv_s[swz(row,g)] = fv;
      }
      __syncthreads();

      if (dh==0){
        float av = alpha_s[pvi];
        #pragma unroll
        for (int k=0;k<4;k++)
          #pragma unroll
          for (int e=0;e<8;e++) oacc[k][e] *= av;
      }
      const float* prow = &p_s[pvi*66];
      #pragma unroll 4
      for (int jj=0;jj<64;jj++){
        float p = prow[jj];
        #pragma unroll
        for (int kk=0;kk<2;kk++){
          int k = 2*dh + kk;
          int g0 = 2*pvd + 8*kk;
          float4 v0 = *(const float4*)&kv_s[swz(jj,g0)];
          float4 v1 = *(const float4*)&kv_s[swz(jj,g0+1)];
          oacc[k][0] = fmaf(p, v0.x, oacc[k][0]);
          oacc[k][1] = fmaf(p, v0.y, oacc[k][1]);
          oacc[k][2] = fmaf(p, v0.z, oacc[k][2]);
          oacc[k][3] = fmaf(p, v0.w, oacc[k][3]);
          oacc[k][4] = fmaf(p, v1.x, oacc[k][4]);
          oacc[k][5] = fmaf(p, v1.y, oacc[k][5]);
          oacc[k][6] = fmaf(p, v1.z, oacc[k][6]);
          oacc[k][7] = fmaf(p, v1.w, oacc[k][7]);
        }
      }
    }
  }

  if (jo==0){
    l_s[r0] = l_run0; l_s[r1] = l_run1;
    lse_g[base_s + iq0] = m_run0 + logf(l_run0);
    lse_g[base_s + iq1] = m_run1 + logf(l_run1);
  }
  __syncthreads();
  float invl = 1.0f / l_s[pvi];
  int oi = iw_s[64 + pvi];
  float* orow = o_r + (base_s + oi)*(size_t)D_HEAD;
  #pragma unroll
  for (int k=0;k<4;k++){
    float4 v0 = {oacc[k][0]*invl, oacc[k][1]*invl, oacc[k][2]*invl, oacc[k][3]*invl};
    float4 v1 = {oacc[k][4]*invl, oacc[k][5]*invl, oacc[k][6]*invl, oacc[k][7]*invl};
    *(float4*)(orow + pvd*8 + k*32)     = v0;
    *(float4*)(orow + pvd*8 + k*32 + 4) = v1;
  }
}

// ---------- combine rounds: softmax over per-round LSE ----------
__global__ __launch_bounds__(256) void combine_kernel(const float* __restrict__ o_r,
                                                      const float* __restrict__ lse,
                                                      float* __restrict__ ocomb)
{
  int gid = blockIdx.x*256 + threadIdx.x;   // B*H*S*32
  int q4 = gid & 31;
  int tokenid = gid >> 5;
  int s = tokenid & (S_LEN-1);
  int h = (tokenid >> 12) & 7;
  int b = tokenid >> 15;
  size_t i0 = (size_t)((b*2 + 0)*8 + h)*S_LEN + s;
  size_t i1 = (size_t)((b*2 + 1)*8 + h)*S_LEN + s;
  float l0 = lse[i0], l1 = lse[i1];
  float m = fmaxf(l0,l1);
  float w0 = expf(l0-m), w1 = expf(l1-m);
  float inv = 1.0f/(w0+w1);
  w0*=inv; w1*=inv;
  float4 a = *(const float4*)(o_r + i0*D_HEAD + q4*4);
  float4 c = *(const float4*)(o_r + i1*D_HEAD + q4*4);
  float4 o = {w0*a.x + w1*c.x, w0*a.y + w1*c.y, w0*a.z + w1*c.z, w0*a.w + w1*c.w};
  *(float4*)(ocomb + (size_t)(s*B_SZ + b)*E_DIM + h*D_HEAD + q4*4) = o;
}

// ---------- launch ----------
extern "C" void kernel_launch(void* const* d_in, const int* in_sizes, int n_in,
                              void* d_out, int out_size, void* d_ws, size_t ws_size,
                              hipStream_t stream)
{
  (void)in_sizes; (void)n_in; (void)out_size; (void)ws_size;
  const float* x  = (const float*)d_in[0];
  const float* wq = (const float*)d_in[1];
  const float* bq = (const float*)d_in[2];
  const float* wv = (const float*)d_in[3];
  const float* bv = (const float*)d_in[4];
  const float* wo = (const float*)d_in[5];
  const float* bo = (const float*)d_in[6];
  const float* hw = (const float*)d_in[7];
  float* out = (float*)d_out;

  float* ws    = (float*)d_ws;
  float* qv    = ws;                          // [8192][2048] q|v
  float* invn  = ws + 16777216;               // [8192]
  float* nrm   = ws + 16785408;               // [8192]
  int*   hashes= (int*)(ws + 16793600);       // [B,R,H,S]
  int*   sidx  = (int*)(ws + 16924672);       // [B,R,H,S]
  float* lse   = ws + 17055744;               // [B,R,H,S]
  float* o_r   = ws + 17186816;               // [B,R,H,S,128]
  float* ocomb = ws + 33964032;               // [8192][1024]
  unsigned short* hs_pack = (unsigned short*)(ws + 42352640);  // [B,R,H,S] packed

  // q projection: fp32, byte-identical accumulation (feeds discrete hash)
  gemm_f32_kernel<<<dim3(8,64), 256, 0, stream>>>(x, wq, bq, wq, bq, 1<<30, qv, 1024, 1024, QV_STRIDE);
  // v projection: bf16 MFMA (smooth path)
  gemm_bf16_kernel<<<dim3(8,64), 256, 0, stream>>>(x, wv, bv, qv + 1024, 1024, QV_STRIDE);
  invnorm_kernel<<<dim3(8192), 256, 0, stream>>>(qv, invn, nrm);
  hash32_kernel<<<dim3(512), 256, 0, stream>>>(qv, nrm, hw, hashes);
  sort_kernel<<<dim3(32), 256, 0, stream>>>(hashes, sidx, hs_pack);
  attn_kernel<<<dim3(2048), 256, 0, stream>>>(qv, invn, sidx, hs_pack, o_r, lse);
  combine_kernel<<<dim3(8192), 256, 0, stream>>>(o_r, lse, ocomb);
  // out projection: bf16 MFMA (smooth path)
  gemm_bf16_kernel<<<dim3(8,64), 256, 0, stream>>>(ocomb, wo, bo, out, 1024, 1024);
}

// Round 7
// 647.208 us; speedup vs baseline: 1.6111x; 1.3145x over previous
//
#include <hip/hip_runtime.h>
#include <hip/hip_bf16.h>
#include <math.h>

// Problem dims
#define S_LEN   4096
#define B_SZ    2
#define E_DIM   1024
#define H_HEADS 8
#define R_ROUNDS 2
#define C_CHUNK 64
#define D_HEAD  128
#define NC_CHUNKS 64
#define QV_STRIDE 2048              // q (1024) | v (1024) per row
#define SCALE_F 0.08838834764831845f
#define NEG_F (-1e9f)
#define NEG_SELF_F (-1e5f)

typedef __attribute__((ext_vector_type(8))) short short8;
typedef __attribute__((ext_vector_type(4))) float f32x4;

// fp32 -> bf16 (RNE) bit pattern
__device__ inline unsigned bfr(float x){
  unsigned u = __float_as_uint(x);
  return (u + 0x7fffu + ((u >> 16) & 1u)) >> 16;
}
__device__ inline unsigned bpack2(float a, float b){ return bfr(a) | (bfr(b) << 16); }
__device__ inline float bf2f(unsigned short v){ return __uint_as_float((unsigned)v << 16); }

// LDS column remap for 128-wide fp32 GEMM tiles
__device__ inline int sm_col(int c){ return ((c & 4) << 4) | ((c >> 3) << 2) | (c & 3); }

// ---------- fp32 tiled GEMM (q projection ONLY) ----------
// Single fp32 FMA chain per output, k ascending — mirrors CPU sgemm so q
// feeding the discrete hash argmax matches reference rounding. DO NOT TOUCH.
__global__ __launch_bounds__(256) void gemm_f32_kernel(
    const float* __restrict__ A, const float* __restrict__ W0, const float* __restrict__ b0,
    const float* __restrict__ W1, const float* __restrict__ b1, int nsplit,
    float* __restrict__ Cout, int N, int K, int ldc)
{
  __shared__ float a_s[32][132];
  __shared__ float w_s[32][132];
  const int t  = threadIdx.x;
  const int n0 = blockIdx.x * 128;
  const int m0 = blockIdx.y * 128;
  const int tx = t & 15, ty = t >> 4;

  float acc[8][8];
  #pragma unroll
  for (int i=0;i<8;i++)
    #pragma unroll
    for (int j=0;j<8;j++) acc[i][j]=0.f;

  const int srow = t >> 3;
  const int scol = (t & 7) * 4;

  for (int kt = 0; kt < K; kt += 32) {
    #pragma unroll
    for (int ii=0; ii<4; ii++) {
      int row = srow + ii*32;
      int pc  = sm_col(row);
      const float4 va = *(const float4*)(A + (size_t)(m0+row)*K + kt + scol);
      a_s[scol+0][pc]=va.x; a_s[scol+1][pc]=va.y; a_s[scol+2][pc]=va.z; a_s[scol+3][pc]=va.w;
      int wrow = n0 + row;
      const float* Wp = (wrow < nsplit) ? (W0 + (size_t)wrow*K) : (W1 + (size_t)(wrow-nsplit)*K);
      const float4 vw = *(const float4*)(Wp + kt + scol);
      w_s[scol+0][pc]=vw.x; w_s[scol+1][pc]=vw.y; w_s[scol+2][pc]=vw.z; w_s[scol+3][pc]=vw.w;
    }
    __syncthreads();
    #pragma unroll 4
    for (int kk=0; kk<32; kk++) {
      float4 a0 = *(const float4*)&a_s[kk][ty*4];
      float4 a1 = *(const float4*)&a_s[kk][64 + ty*4];
      float4 w0v = *(const float4*)&w_s[kk][tx*4];
      float4 w1v = *(const float4*)&w_s[kk][64 + tx*4];
      float am[8] = {a0.x,a0.y,a0.z,a0.w,a1.x,a1.y,a1.z,a1.w};
      float wm[8] = {w0v.x,w0v.y,w0v.z,w0v.w,w1v.x,w1v.y,w1v.z,w1v.w};
      #pragma unroll
      for (int i=0;i<8;i++)
        #pragma unroll
        for (int j=0;j<8;j++)
          acc[i][j] = fmaf(am[i], wm[j], acc[i][j]);
    }
    __syncthreads();
  }
  float bias[8];
  #pragma unroll
  for (int j=0;j<8;j++){
    int n = n0 + tx*8 + j;
    bias[j] = (n < nsplit) ? b0[n] : b1[n-nsplit];
  }
  #pragma unroll
  for (int i=0;i<8;i++){
    int row = m0 + ty*8 + i;
    float4 o0 = {acc[i][0]+bias[0], acc[i][1]+bias[1], acc[i][2]+bias[2], acc[i][3]+bias[3]};
    float4 o1 = {acc[i][4]+bias[4], acc[i][5]+bias[5], acc[i][6]+bias[6], acc[i][7]+bias[7]};
    *(float4*)(Cout + (size_t)row*ldc + n0 + tx*8)     = o0;
    *(float4*)(Cout + (size_t)row*ldc + n0 + tx*8 + 4) = o1;
  }
}

// ---------- bf16 MFMA GEMM (v-proj, out-proj) — R6-validated ----------
#define BST 72
__global__ __launch_bounds__(256) void gemm_bf16_kernel(
    const float* __restrict__ A, const float* __restrict__ W,
    const float* __restrict__ bias, float* __restrict__ C,
    int K, int ldc)
{
  __shared__ unsigned short a_sh[128*BST];
  __shared__ unsigned short w_sh[128*BST];
  const int t = threadIdx.x;
  const int m0 = blockIdx.y * 128, n0 = blockIdx.x * 128;
  const int lane = t & 63, wid = t >> 6;
  const int mw = (wid >> 1) * 64, nw = (wid & 1) * 64;
  const int lr = lane & 15, lg = lane >> 4;

  f32x4 acc[4][4];
  #pragma unroll
  for (int i=0;i<4;i++)
    #pragma unroll
    for (int j=0;j<4;j++) acc[i][j] = (f32x4){0.f,0.f,0.f,0.f};

  const int srow = t >> 3;
  const int scol = (t & 7) * 8;

  for (int kt = 0; kt < K; kt += 64){
    __syncthreads();
    #pragma unroll
    for (int ii = 0; ii < 4; ii++){
      int row = srow + ii*32;
      const float4 f0 = *(const float4*)(A + (size_t)(m0+row)*K + kt + scol);
      const float4 f1 = *(const float4*)(A + (size_t)(m0+row)*K + kt + scol + 4);
      uint4 ua = { bpack2(f0.x,f0.y), bpack2(f0.z,f0.w), bpack2(f1.x,f1.y), bpack2(f1.z,f1.w) };
      *(uint4*)&a_sh[row*BST + scol] = ua;
      const float4 g0 = *(const float4*)(W + (size_t)(n0+row)*K + kt + scol);
      const float4 g1 = *(const float4*)(W + (size_t)(n0+row)*K + kt + scol + 4);
      uint4 uw = { bpack2(g0.x,g0.y), bpack2(g0.z,g0.w), bpack2(g1.x,g1.y), bpack2(g1.z,g1.w) };
      *(uint4*)&w_sh[row*BST + scol] = uw;
    }
    __syncthreads();
    #pragma unroll
    for (int ks = 0; ks < 64; ks += 32){
      short8 af[4], bw[4];
      #pragma unroll
      for (int i=0;i<4;i++) af[i] = *(const short8*)&a_sh[(mw + i*16 + lr)*BST + ks + lg*8];
      #pragma unroll
      for (int j=0;j<4;j++) bw[j] = *(const short8*)&w_sh[(nw + j*16 + lr)*BST + ks + lg*8];
      #pragma unroll
      for (int i=0;i<4;i++)
        #pragma unroll
        for (int j=0;j<4;j++)
          acc[i][j] = __builtin_amdgcn_mfma_f32_16x16x32_bf16(af[i], bw[j], acc[i][j], 0, 0, 0);
    }
  }
  #pragma unroll
  for (int j=0;j<4;j++){
    int col = n0 + nw + j*16 + lr;
    float bs = bias[col];
    #pragma unroll
    for (int i=0;i<4;i++){
      int rbase = m0 + mw + i*16 + lg*4;
      #pragma unroll
      for (int r=0;r<4;r++)
        C[(size_t)(rbase+r)*ldc + col] = acc[i][j][r] + bs;
    }
  }
}

// ---------- per-row norm over E ----------
__global__ __launch_bounds__(256) void invnorm_kernel(const float* __restrict__ qv,
                                                      float* __restrict__ invn,
                                                      float* __restrict__ nrm)
{
  int row = blockIdx.x;
  int t = threadIdx.x;
  float4 v = *(const float4*)(qv + (size_t)row*QV_STRIDE + t*4);
  float ss = v.x*v.x + v.y*v.y + v.z*v.z + v.w*v.w;
  #pragma unroll
  for (int off=32; off; off>>=1) ss += __shfl_down(ss, off);
  __shared__ float part[4];
  if ((t & 63)==0) part[t>>6] = ss;
  __syncthreads();
  if (t==0){
    float n = sqrtf(part[0]+part[1]+part[2]+part[3]);
    nrm[row]  = n;
    invn[row] = 1.0f/n;
  }
}

// ---------- fp32 hash path, reference-order mimicry (R5 pass; DO NOT TOUCH) ----------
__global__ __launch_bounds__(256) void hash32_kernel(
    const float* __restrict__ qv, const float* __restrict__ nrm,
    const float* __restrict__ hw, int* __restrict__ hashes)
{
  int idx = blockIdx.x*256 + threadIdx.x;
  int s = idx & (S_LEN-1);
  int h = (idx >> 12) & 7;
  int r = (idx >> 15) & 1;
  int b = idx >> 16;
  const float* qr = qv + (size_t)(s*B_SZ + b)*QV_STRIDE + h*D_HEAD;
  const float  n  = nrm[s*B_SZ + b];
  const float* wp = hw + (size_t)(r*H_HEADS + h)*D_HEAD*8;
  float lin[8];
  #pragma unroll
  for (int m=0;m<8;m++) lin[m]=0.f;
  for (int d=0; d<D_HEAD; d++){
    float kd = qr[d] / n;
    #pragma unroll
    for (int m=0;m<8;m++) lin[m] = fmaf(kd, wp[d*8+m], lin[m]);
  }
  float best = lin[0]; int bi = 0;
  #pragma unroll
  for (int m=1;m<8;m++) if (lin[m] > best){ best=lin[m]; bi=m; }
  #pragma unroll
  for (int m=0;m<8;m++) if (-lin[m] > best){ best=-lin[m]; bi=8+m; }
  hashes[idx] = bi;
}

// ---------- stable counting sort by bucket, per (b,r,h) ----------
__global__ __launch_bounds__(256) void sort_kernel(const int* __restrict__ hashes,
                                                   int* __restrict__ sidx,
                                                   unsigned short* __restrict__ hs_pack)
{
  __shared__ unsigned char bucket_s[S_LEN];
  __shared__ int counts[16][257];
  __shared__ int bbase[16];
  int t = threadIdx.x;
  size_t base = (size_t)blockIdx.x * S_LEN;
  for (int e=0;e<16;e++) bucket_s[t + e*256] = (unsigned char)hashes[base + t + e*256];
  #pragma unroll
  for (int u=0;u<16;u++) counts[u][t]=0;
  if (t<16) counts[t][256]=0;
  __syncthreads();
  int s0 = t*16;
  for (int e=0;e<16;e++){ int u = bucket_s[s0+e]; counts[u][t]++; }
  __syncthreads();
  if (t < 16){
    int run=0;
    for (int tt=0; tt<256; tt++){ int c = counts[t][tt]; counts[t][tt]=run; run+=c; }
    counts[t][256]=run;
  }
  __syncthreads();
  if (t==0){
    int run=0;
    for (int u=0;u<16;u++){ bbase[u]=run; run += counts[u][256]; }
  }
  __syncthreads();
  for (int e=0;e<16;e++){
    int s = s0+e; int u = bucket_s[s];
    int pos = bbase[u] + counts[u][t]; counts[u][t]++;
    sidx[base+pos] = s;
    hs_pack[base+pos] = (unsigned short)(s | (u<<12));
  }
}

// ---------- gather: sorted bf16 K-hat rows + transposed V ----------
// ksort[brh][pos][d]  = q[token][h,d] * invn[token]   (bf16)
// vsortT[brh][d][pos] = v[token][h,d]                 (bf16, transposed in LDS)
#define GST 136
__global__ __launch_bounds__(256) void gather_kernel(
    const float* __restrict__ qv, const float* __restrict__ invn,
    const int* __restrict__ sidx,
    unsigned short* __restrict__ ksort, unsigned short* __restrict__ vsortT)
{
  __shared__ int tok_s[256];
  __shared__ float sc_s[256];
  __shared__ unsigned short v_sub[64*GST];
  const int t = threadIdx.x;
  const int brh = blockIdx.x >> 4, pc = blockIdx.x & 15;
  const int b = brh >> 4;
  const int h = brh & 7;
  const size_t base_s = (size_t)brh * S_LEN;
  const int pos0 = pc * 256;
  {
    int tok = sidx[base_s + pos0 + t];
    tok_s[t] = tok;
    sc_s[t] = invn[tok*B_SZ + b];
  }
  __syncthreads();
  // ksort: coalesced row-major bf16
  #pragma unroll 4
  for (int i=0;i<16;i++){
    int slot = i*256 + t;
    int pos = slot >> 4, g = slot & 15;
    int tok = tok_s[pos]; float sc = sc_s[pos];
    const float* src = qv + ((size_t)tok*B_SZ + b)*QV_STRIDE + h*D_HEAD + g*8;
    float4 f0 = *(const float4*)src, f1 = *(const float4*)(src+4);
    uint4 u = { bpack2(f0.x*sc, f0.y*sc), bpack2(f0.z*sc, f0.w*sc),
                bpack2(f1.x*sc, f1.y*sc), bpack2(f1.z*sc, f1.w*sc) };
    *(uint4*)&ksort[(base_s + pos0 + pos)*128 + g*8] = u;
  }
  // vsortT: 4 sub-tiles of 64 pos, LDS transpose
  for (int sub=0; sub<4; sub++){
    __syncthreads();
    #pragma unroll
    for (int i=0;i<4;i++){
      int slot = i*256 + t;
      int pr = slot >> 4, g = slot & 15;
      int tok = tok_s[sub*64 + pr];
      const float* src = qv + ((size_t)tok*B_SZ + b)*QV_STRIDE + 1024 + h*D_HEAD + g*8;
      float4 f0 = *(const float4*)src, f1 = *(const float4*)(src+4);
      uint4 u = { bpack2(f0.x,f0.y), bpack2(f0.z,f0.w), bpack2(f1.x,f1.y), bpack2(f1.z,f1.w) };
      *(uint4*)&v_sub[pr*GST + g*8] = u;
    }
    __syncthreads();
    #pragma unroll
    for (int i=0;i<8;i++){
      int oslot = i*256 + t;             // 2048 = 128 d x 16 pos-groups
      int d = oslot >> 4, p4 = (oslot & 15)*4;
      unsigned a0 = v_sub[(p4+0)*GST + d];
      unsigned a1 = v_sub[(p4+1)*GST + d];
      unsigned a2 = v_sub[(p4+2)*GST + d];
      unsigned a3 = v_sub[(p4+3)*GST + d];
      uint2 o = { a0 | (a1<<16), a2 | (a3<<16) };
      *(uint2*)&vsortT[(size_t)brh*524288 + (size_t)d*4096 + pos0 + sub*64 + p4] = o;
    }
  }
}

// ---------- MFMA chunked LSH attention ----------
// Reference quirk (silent broadcast): for query at sorted position p=n*64+c,
// scores/values use win(n), but BOTH masks compare vs win(c).
// S rows post-scaled by SCALE*nrm[token] (Q = k-hat * SCALE*nrm exactly up to
// smooth fp noise). Full 192-wide softmax in registers; P via LDS (bf16).
#define KST 136
#define VST 72
#define PST 200
__device__ inline int swzg(int row, int g){ return (g ^ (row & 7)) << 3; }

__global__ __launch_bounds__(256) void attn_mfma_kernel(
    const unsigned short* __restrict__ ksort, const unsigned short* __restrict__ vsortT,
    const float* __restrict__ nrm, const unsigned short* __restrict__ hs_pack,
    unsigned short* __restrict__ o_r16, float* __restrict__ lse_g)
{
  __shared__ unsigned short kv_un[128*VST];          // 9216 u16: K chunk (64x136) or V^T chunk (128x72)
  __shared__ unsigned short p_sh[64*PST];
  __shared__ __align__(16) unsigned short pack_s[S_LEN];
  __shared__ float srow_s[64];

  const int t = threadIdx.x;
  const int bid = blockIdx.x;
  const int nc = bid & 63;
  const int brh = bid >> 6;
  const int b = brh >> 4;
  const size_t base_s = (size_t)brh * S_LEN;

  {
    const uint4* src = (const uint4*)(hs_pack + base_s);
    uint4* dst = (uint4*)pack_s;
    dst[t]       = src[t];
    dst[256 + t] = src[256 + t];
  }
  __syncthreads();
  if (t < 64){
    int tok = pack_s[nc*64 + t] & 0xfff;
    srow_s[t] = SCALE_F * nrm[tok*B_SZ + b];
  }

  const int lane = t & 63, wid = t >> 6;
  const int mw = wid * 16;                 // wave's 16 query rows
  const int lr = lane & 15, lg = lane >> 4;

  f32x4 acc[12];
  #pragma unroll
  for (int i=0;i<12;i++) acc[i] = (f32x4){0.f,0.f,0.f,0.f};
  short8 aq[4];

  // ---- QK^T: window chunks, w=1 first (supplies Q fragments) ----
  const int worder[3] = {1, 0, 2};
  #pragma unroll
  for (int wi=0; wi<3; wi++){
    int w = worder[wi];
    int cwch = (nc + w + 63) & 63;
    __syncthreads();                       // also covers srow_s on first iter
    #pragma unroll
    for (int i=0;i<4;i++){
      int slot = i*256 + t;
      int row = slot >> 4, g = slot & 15;
      uint4 u = *(const uint4*)&ksort[(base_s + cwch*64 + row)*128 + g*8];
      *(uint4*)&kv_un[row*KST + swzg(row, g)] = u;
    }
    __syncthreads();
    if (wi==0){
      #pragma unroll
      for (int ks=0; ks<4; ks++)
        aq[ks] = *(const short8*)&kv_un[(mw+lr)*KST + swzg(mw+lr, ks*4+lg)];
    }
    #pragma unroll
    for (int ks=0; ks<4; ks++){
      #pragma unroll
      for (int k4=0; k4<4; k4++){
        short8 bk = *(const short8*)&kv_un[(k4*16+lr)*KST + swzg(k4*16+lr, ks*4+lg)];
        acc[w*4+k4] = __builtin_amdgcn_mfma_f32_16x16x32_bf16(aq[ks], bk, acc[w*4+k4], 0,0,0);
      }
    }
  }

  // ---- scale + masks + softmax (C-layout: col=lr, rows mw+lg*4+r) ----
  unsigned pq[4]; float sr[4]; int c_[4]; float linv[4];
  #pragma unroll
  for (int r=0;r<4;r++){
    c_[r] = mw + lg*4 + r;
    pq[r] = pack_s[nc*64 + c_[r]];
    sr[r] = srow_s[c_[r]];
  }
  #pragma unroll
  for (int ti=0; ti<12; ti++){
    int w = ti >> 2, k4 = ti & 3;
    #pragma unroll
    for (int r=0;r<4;r++){
      int mc = (c_[r] + w + 63) & 63;
      unsigned e = pack_s[mc*64 + k4*16 + lr];
      float s = acc[ti][r] * sr[r];
      s = ((e>>12) == (pq[r]>>12)) ? s : NEG_F;
      if ((e & 0xfffu) == (pq[r] & 0xfffu)) s = NEG_SELF_F;
      acc[ti][r] = s;
    }
  }
  #pragma unroll
  for (int r=0;r<4;r++){
    float m = acc[0][r];
    #pragma unroll
    for (int ti=1; ti<12; ti++) m = fmaxf(m, acc[ti][r]);
    #pragma unroll
    for (int off=1; off<16; off<<=1) m = fmaxf(m, __shfl_xor(m, off));
    float l = 0.f;
    #pragma unroll
    for (int ti=0; ti<12; ti++){
      float p = __expf(acc[ti][r] - m);
      l += p;
      int wpos = (ti>>2)*64 + (ti&3)*16 + lr;
      p_sh[c_[r]*PST + (((wpos>>3) ^ (c_[r]&7))<<3) + (wpos&7)] = (unsigned short)bfr(p);
    }
    #pragma unroll
    for (int off=1; off<16; off<<=1) l += __shfl_xor(l, off);
    linv[r] = 1.0f / l;
    if (lr == 0) lse_g[base_s + (pq[r] & 0xfffu)] = m + logf(l);
  }

  // ---- PV ----
  f32x4 oacc[8];
  #pragma unroll
  for (int i=0;i<8;i++) oacc[i] = (f32x4){0.f,0.f,0.f,0.f};
  for (int w=0; w<3; w++){
    int cwch = (nc + w + 63) & 63;
    __syncthreads();                       // p_sh written; kv_un free
    #pragma unroll
    for (int i=0;i<4;i++){
      int slot = i*256 + t;                // 1024 = 128 d x 8 key-groups
      int d = slot >> 3, kg = slot & 7;
      uint4 u = *(const uint4*)&vsortT[(size_t)brh*524288 + (size_t)d*4096 + cwch*64 + kg*8];
      *(uint4*)&kv_un[d*VST + swzg(d, kg)] = u;
    }
    __syncthreads();
    short8 ap[2];
    #pragma unroll
    for (int ks=0; ks<2; ks++){
      int g = w*8 + ks*4 + lg;
      ap[ks] = *(const short8*)&p_sh[(mw+lr)*PST + ((g ^ ((mw+lr)&7))<<3)];
    }
    #pragma unroll
    for (int ks=0; ks<2; ks++)
      #pragma unroll
      for (int dt=0; dt<8; dt++){
        short8 bv = *(const short8*)&kv_un[(dt*16+lr)*VST + swzg(dt*16+lr, ks*4+lg)];
        oacc[dt] = __builtin_amdgcn_mfma_f32_16x16x32_bf16(ap[ks], bv, oacc[dt], 0,0,0);
      }
  }

  // ---- epilogue: bf16 scatter by token ----
  #pragma unroll
  for (int r=0;r<4;r++){
    int tok = pq[r] & 0xfff;
    size_t ob = (base_s + tok) * 128;
    #pragma unroll
    for (int dt=0; dt<8; dt++)
      o_r16[ob + dt*16 + lr] = (unsigned short)bfr(oacc[dt][r] * linv[r]);
  }
}

// ---------- combine rounds: softmax over per-round LSE (o_r now bf16) ----------
__global__ __launch_bounds__(256) void combine_kernel(const unsigned short* __restrict__ o_r16,
                                                      const float* __restrict__ lse,
                                                      float* __restrict__ ocomb)
{
  int gid = blockIdx.x*256 + threadIdx.x;
  int q4 = gid & 31;
  int tokenid = gid >> 5;
  int s = tokenid & (S_LEN-1);
  int h = (tokenid >> 12) & 7;
  int b = tokenid >> 15;
  size_t i0 = (size_t)((b*2 + 0)*8 + h)*S_LEN + s;
  size_t i1 = (size_t)((b*2 + 1)*8 + h)*S_LEN + s;
  float l0 = lse[i0], l1 = lse[i1];
  float m = fmaxf(l0,l1);
  float w0 = expf(l0-m), w1 = expf(l1-m);
  float inv = 1.0f/(w0+w1);
  w0*=inv; w1*=inv;
  const unsigned short* p0 = o_r16 + i0*128 + q4*4;
  const unsigned short* p1 = o_r16 + i1*128 + q4*4;
  float4 o = { w0*bf2f(p0[0]) + w1*bf2f(p1[0]),
               w0*bf2f(p0[1]) + w1*bf2f(p1[1]),
               w0*bf2f(p0[2]) + w1*bf2f(p1[2]),
               w0*bf2f(p0[3]) + w1*bf2f(p1[3]) };
  *(float4*)(ocomb + (size_t)(s*B_SZ + b)*E_DIM + h*D_HEAD + q4*4) = o;
}

// ---------- launch ----------
extern "C" void kernel_launch(void* const* d_in, const int* in_sizes, int n_in,
                              void* d_out, int out_size, void* d_ws, size_t ws_size,
                              hipStream_t stream)
{
  (void)in_sizes; (void)n_in; (void)out_size; (void)ws_size;
  const float* x  = (const float*)d_in[0];
  const float* wq = (const float*)d_in[1];
  const float* bq = (const float*)d_in[2];
  const float* wv = (const float*)d_in[3];
  const float* bv = (const float*)d_in[4];
  const float* wo = (const float*)d_in[5];
  const float* bo = (const float*)d_in[6];
  const float* hw = (const float*)d_in[7];
  float* out = (float*)d_out;

  float* ws    = (float*)d_ws;
  float* qv    = ws;                          // [8192][2048] q|v fp32
  float* invn  = ws + 16777216;               // [8192]
  float* nrm   = ws + 16785408;               // [8192]
  int*   hashes= (int*)(ws + 16793600);       // [B,R,H,S]
  int*   sidx  = (int*)(ws + 16924672);       // [B,R,H,S]
  float* lse   = ws + 17055744;               // [B,R,H,S]
  unsigned short* o_r16   = (unsigned short*)(ws + 17186816);  // [32][4096][128] bf16
  unsigned short* ksort   = (unsigned short*)(ws + 25575424);  // [32][4096][128] bf16
  float* ocomb = ws + 33964032;               // [8192][1024] fp32
  unsigned short* vsortT  = (unsigned short*)(ws + 33964032);  // [32][128][4096] bf16 (overlays ocomb; dead before combine writes)
  unsigned short* hs_pack = (unsigned short*)(ws + 42352640);  // [B,R,H,S] packed

  gemm_f32_kernel<<<dim3(8,64), 256, 0, stream>>>(x, wq, bq, wq, bq, 1<<30, qv, 1024, 1024, QV_STRIDE);
  gemm_bf16_kernel<<<dim3(8,64), 256, 0, stream>>>(x, wv, bv, qv + 1024, 1024, QV_STRIDE);
  invnorm_kernel<<<dim3(8192), 256, 0, stream>>>(qv, invn, nrm);
  hash32_kernel<<<dim3(512), 256, 0, stream>>>(qv, nrm, hw, hashes);
  sort_kernel<<<dim3(32), 256, 0, stream>>>(hashes, sidx, hs_pack);
  gather_kernel<<<dim3(512), 256, 0, stream>>>(qv, invn, sidx, ksort, vsortT);
  attn_mfma_kernel<<<dim3(2048), 256, 0, stream>>>(ksort, vsortT, nrm, hs_pack, o_r16, lse);
  combine_kernel<<<dim3(8192), 256, 0, stream>>>(o_r16, lse, ocomb);
  gemm_bf16_kernel<<<dim3(8,64), 256, 0, stream>>>(ocomb, wo, bo, out, 1024, 1024);
}